// Round 2
// baseline (19608.647 us; speedup 1.0000x reference)
//
#include <hip/hip_runtime.h>

// LSTM B=1024 T=512 H=256 (input_size=1, output_size=1) on MI355X.
// R6: pair-split. R5 post-mortem: __launch_bounds__ 2nd arg acts as min
// BLOCKS/CU on this compiler ((512,2)->128 VGPR cap, (1024,4)->64 cap ->
// scratch spill, 2.5x regression). Deeper issue shared by R4/R5: only 64/256
// CUs used and ~256KB/step of static weights re-read from LDS (~3000cy floor).
// New structure: 128 blocks x 512 thr (8 waves). Pair (bid, bid^8) shares 16
// batch rows; member q=(bid>>3)&1 owns hidden cols [128q,128q+128) and ALL
// FOUR of its gate tiles fully register-resident (4 gates x 8 kc x 32B =
// 128 VGPR/thread; ~205 total, cap 256 via __launch_bounds__(512,1)).
// Zero per-step weight traffic. Per step: publish own 16x128 h-half (4KB)
// via agent-scope 8B atomic stores + per-wave release atomicAdd flag;
// consume partner half via acquire poll + agent-scope atomic loads (L3 is
// the coherent point; bid^8 likely same XCD via %8 round-robin, but
// correctness doesn't depend on it). Co-residency guaranteed: 128 blocks
// <= 256 CUs, >=1 block fits per CU -> every block resident -> no deadlock.
// Flags in d_ws, zeroed by hipMemsetAsync each launch. One barrier/step.

#define HID 256
#define TT 512
#define NBLK 128
#define THREADS 512
#define HPAD2 136   // 128 local cols + 8 pad (ushort units)

typedef float v4f __attribute__((ext_vector_type(4)));
typedef unsigned int v4u __attribute__((ext_vector_type(4)));
typedef unsigned long long v2ul __attribute__((ext_vector_type(2)));
typedef __bf16 v8bf __attribute__((ext_vector_type(8)));

__device__ __forceinline__ unsigned short f2bf(float f) {
    unsigned int u = __builtin_bit_cast(unsigned int, f);
    u += 0x7fffu + ((u >> 16) & 1u);   // RNE
    return (unsigned short)(u >> 16);
}
__device__ __forceinline__ float bf2f(unsigned short s) {
    unsigned int u = ((unsigned int)s) << 16;
    return __builtin_bit_cast(float, u);
}
__device__ __forceinline__ float fsigmoid(float x) {
    float e = exp2f(x * -1.44269504f);
    return __builtin_amdgcn_rcpf(1.0f + e);
}
__device__ __forceinline__ float ftanh(float x) {
    float e = exp2f(x * 2.88539008f);
    return 1.0f - 2.0f * __builtin_amdgcn_rcpf(1.0f + e);
}

// W_hh fp32 [1024][256] -> bf16 fragment order:
// Wbf[((Tn*8+kc)*64+lane)*8 + j] = bf16(W_hh[16*Tn+(lane&15)][32*kc+(lane>>4)*8+j])
__global__ void wconv_kernel(const float* __restrict__ Whh,
                             unsigned short* __restrict__ Wbf) {
    int tid = blockIdx.x * blockDim.x + threadIdx.x;   // 0..32767
    int lane = tid & 63;
    int frag = tid >> 6;
    int Tn = frag >> 3;
    int kc = frag & 7;
    int n  = Tn * 16 + (lane & 15);
    int kb = kc * 32 + (lane >> 4) * 8;
    const float* src = Whh + (size_t)n * HID + kb;
    unsigned short* dst = Wbf + (size_t)tid * 8;
#pragma unroll
    for (int j = 0; j < 8; ++j) dst[j] = f2bf(src[j]);
}

#define MFMA_BF16 __builtin_amdgcn_mfma_f32_16x16x32_bf16

__global__ __launch_bounds__(THREADS, 1)
void lstm_kernel(const float* __restrict__ x,
                 const float* __restrict__ W_ih,
                 const float* __restrict__ b_ih,
                 const float* __restrict__ b_hh,
                 const float* __restrict__ W_lin,
                 const float* __restrict__ b_lin,
                 const unsigned short* __restrict__ Wbf,
                 unsigned short* __restrict__ Hx,
                 int* __restrict__ flags,
                 float* __restrict__ out) {
    __shared__ __align__(16) unsigned short hbuf[2][16 * HPAD2];  // 8.7 KB
    __shared__ float part[THREADS];                               // 2 KB

    const int tid  = threadIdx.x;
    const int lane = tid & 63;
    const int w    = tid >> 6;      // wave 0..7
    const int l4   = lane & 15;
    const int quad = lane >> 4;

    const int bid = blockIdx.x;
    const int q   = (bid >> 3) & 1;                 // gate-half role
    const int p   = (bid >> 4) * 8 + (bid & 7);     // pair id 0..63
    const int r0  = p * 16;                         // batch rows [r0, r0+16)

    // Hx layout: [parity][pair][q][16 rows][128 cols] bf16; parity stride:
    const size_t PSTR = (size_t)64 * 2 * 2048;
    unsigned short* HxMine       = Hx + (size_t)(p * 2 + q) * 2048;
    const unsigned short* HxPart = Hx + (size_t)(p * 2 + (1 - q)) * 2048;
    int* flagMine = flags + (p * 2 + q) * 32;       // 128B-spaced
    int* flagPart = flags + (p * 2 + (1 - q)) * 32;

    // all 4 gate tiles register-resident: wv[G][kc], kc = global K chunk
    v8bf wv[4][8];
    {
        int n = 8 * q + w;   // col-tile index 0..15
#pragma unroll
        for (int G = 0; G < 4; ++G) {
            int Tn = 16 * G + n;
#pragma unroll
            for (int kc = 0; kc < 8; ++kc)
                wv[G][kc] = __builtin_bit_cast(v8bf,
                    *(const v4u*)(Wbf + ((size_t)(Tn * 8 + kc) * 64 + lane) * 8));
        }
    }

    // per-thread gate constants
    const int col = 128 * q + 16 * w + l4;          // global hidden col
    const float cwi = W_ih[col],       cbi = b_ih[col]       + b_hh[col];
    const float cwf = W_ih[256 + col], cbf = b_ih[256 + col] + b_hh[256 + col];
    const float cwg = W_ih[512 + col], cbg = b_ih[512 + col] + b_hh[512 + col];
    const float cwo = W_ih[768 + col], cbo = b_ih[768 + col] + b_hh[768 + col];

    for (int i = tid; i < 16 * HPAD2; i += THREADS) hbuf[0][i] = 0;

    float xv[4];
#pragma unroll
    for (int r = 0; r < 4; ++r) xv[r] = x[(size_t)(r0 + quad * 4 + r) * TT];

    __syncthreads();

    float c_st[4] = {0.f, 0.f, 0.f, 0.f};
    int cur = 0;
    const int kOwn = 4 * q, kPart = 4 * (1 - q);

    for (int t = 0; t < TT; ++t) {
        const unsigned short* hrow = hbuf[cur] + l4 * HPAD2 + quad * 8;
        unsigned short* hn = hbuf[cur ^ 1];

        v4f ai, af, ag, ao;
#pragma unroll
        for (int r = 0; r < 4; ++r) {
            ai[r] = xv[r] * cwi + cbi;
            af[r] = xv[r] * cwf + cbf;
            ag[r] = xv[r] * cwg + cbg;
            ao[r] = xv[r] * cwo + cbo;
        }

        // own-half A fragments from LDS (local cols 0..127)
        v8bf aOwn[4];
#pragma unroll
        for (int k = 0; k < 4; ++k)
            aOwn[k] = __builtin_bit_cast(v8bf, *(const v4u*)(hrow + k * 32));

        // partner-half A fragments from L3 (agent-scope atomic 8B loads)
        v8bf aP[4];
        if (t > 0) {
            while (__hip_atomic_load(flagPart, __ATOMIC_ACQUIRE,
                                     __HIP_MEMORY_SCOPE_AGENT) < 8 * t)
                __builtin_amdgcn_s_sleep(1);
            const unsigned long long* pb = (const unsigned long long*)
                (HxPart + ((t & 1) ? PSTR : 0) + l4 * 128 + quad * 8);
#pragma unroll
            for (int k = 0; k < 4; ++k) {
                v2ul tt;
                tt[0] = __hip_atomic_load(pb + k * 8, __ATOMIC_RELAXED,
                                          __HIP_MEMORY_SCOPE_AGENT);
                tt[1] = __hip_atomic_load(pb + k * 8 + 1, __ATOMIC_RELAXED,
                                          __HIP_MEMORY_SCOPE_AGENT);
                aP[k] = __builtin_bit_cast(v8bf, tt);
            }
        } else {
#pragma unroll
            for (int k = 0; k < 4; ++k)
                aP[k] = __builtin_bit_cast(v8bf, (v4u)(0u));
        }

        // own-half MFMAs first (cover partner-load latency), then partner
#pragma unroll
        for (int k = 0; k < 4; ++k) {
            ai = MFMA_BF16(aOwn[k], wv[0][kOwn + k], ai, 0, 0, 0);
            af = MFMA_BF16(aOwn[k], wv[1][kOwn + k], af, 0, 0, 0);
            ag = MFMA_BF16(aOwn[k], wv[2][kOwn + k], ag, 0, 0, 0);
            ao = MFMA_BF16(aOwn[k], wv[3][kOwn + k], ao, 0, 0, 0);
        }
#pragma unroll
        for (int k = 0; k < 4; ++k) {
            ai = MFMA_BF16(aP[k], wv[0][kPart + k], ai, 0, 0, 0);
            af = MFMA_BF16(aP[k], wv[1][kPart + k], af, 0, 0, 0);
            ag = MFMA_BF16(aP[k], wv[2][kPart + k], ag, 0, 0, 0);
            ao = MFMA_BF16(aP[k], wv[3][kPart + k], ao, 0, 0, 0);
        }

#pragma unroll
        for (int r = 0; r < 4; ++r) {
            float gi = fsigmoid(ai[r]);
            float gf = fsigmoid(af[r]);
            float gg = ftanh(ag[r]);
            float go = fsigmoid(ao[r]);
            float cn = gf * c_st[r] + gi * gg;
            c_st[r] = cn;
            hn[(quad * 4 + r) * HPAD2 + 16 * w + l4] = f2bf(go * ftanh(cn));
        }
        __syncthreads();

        // publish own half: [16][128] row-major, 8B per thread from LDS
        {
            int rr = tid >> 5, ch = tid & 31;
            unsigned long long v =
                *(const unsigned long long*)(hn + rr * HPAD2 + ch * 4);
            __hip_atomic_store((unsigned long long*)
                (HxMine + (((t + 1) & 1) ? PSTR : 0) + rr * 128 + ch * 4),
                v, __ATOMIC_RELAXED, __HIP_MEMORY_SCOPE_AGENT);
        }
        asm volatile("s_waitcnt vmcnt(0)" ::: "memory");
        if (lane == 0)
            __hip_atomic_fetch_add(flagMine, 1, __ATOMIC_RELEASE,
                                   __HIP_MEMORY_SCOPE_AGENT);

        // x prefetch for t+1 (wraps harmlessly)
        {
            int tn = (t + 1) & (TT - 1);
#pragma unroll
            for (int r = 0; r < 4; ++r)
                xv[r] = x[(size_t)(r0 + quad * 4 + r) * TT + tn];
        }
        cur ^= 1;
    }

    // Epilogue: q=0 combines both halves; final h is hbuf[cur] (own) +
    // HxPart parity slot (512&1)=0 (partner, flag target 8*512).
    if (q == 0) {
        while (__hip_atomic_load(flagPart, __ATOMIC_ACQUIRE,
                                 __HIP_MEMORY_SCOPE_AGENT) < 8 * TT)
            __builtin_amdgcn_s_sleep(1);
        int rr = tid >> 5, ch = tid & 31;
        float ps = 0.f;
        if (ch < 16) {   // cols 0..127 from LDS
            const unsigned short* hb = hbuf[cur] + rr * HPAD2 + ch * 8;
#pragma unroll
            for (int jj = 0; jj < 8; ++jj)
                ps += bf2f(hb[jj]) * W_lin[ch * 8 + jj];
        } else {         // cols 128..255 from partner
            const unsigned long long* pb = (const unsigned long long*)
                (HxPart + rr * 128 + (ch - 16) * 8);
            unsigned long long lo = __hip_atomic_load(pb, __ATOMIC_RELAXED,
                                                      __HIP_MEMORY_SCOPE_AGENT);
            unsigned long long hi = __hip_atomic_load(pb + 1, __ATOMIC_RELAXED,
                                                      __HIP_MEMORY_SCOPE_AGENT);
            int cb = 128 + (ch - 16) * 8;
#pragma unroll
            for (int jj = 0; jj < 4; ++jj) {
                ps += bf2f((unsigned short)(lo >> (16 * jj))) * W_lin[cb + jj];
                ps += bf2f((unsigned short)(hi >> (16 * jj))) * W_lin[cb + 4 + jj];
            }
        }
        part[tid] = ps;
        __syncthreads();
        if (tid < 16) {
            float sum = 0.f;
#pragma unroll
            for (int s = 0; s < 32; ++s) sum += part[tid * 32 + s];
            out[r0 + tid] = sum + b_lin[0];
        }
    }
}

extern "C" void kernel_launch(void* const* d_in, const int* in_sizes, int n_in,
                              void* d_out, int out_size, void* d_ws, size_t ws_size,
                              hipStream_t stream) {
    const float* x     = (const float*)d_in[0];
    const float* W_ih  = (const float*)d_in[1];
    const float* W_hh  = (const float*)d_in[2];
    const float* b_ih  = (const float*)d_in[3];
    const float* b_hh  = (const float*)d_in[4];
    const float* W_lin = (const float*)d_in[5];
    const float* b_lin = (const float*)d_in[6];

    unsigned short* Wbf = (unsigned short*)d_ws;                          // 512 KB
    unsigned short* Hx  = (unsigned short*)((char*)d_ws + (512 << 10));   // 1 MB
    int* flags          = (int*)((char*)d_ws + (512 << 10) + (1024 << 10)); // 16 KB

    hipMemsetAsync(flags, 0, 64 * 2 * 32 * sizeof(int), stream);
    wconv_kernel<<<128, 256, 0, stream>>>(W_hh, Wbf);
    lstm_kernel<<<NBLK, THREADS, 0, stream>>>(x, W_ih, b_ih, b_hh, W_lin, b_lin,
                                              Wbf, Hx, flags, (float*)d_out);
}

// Round 3
// 12435.007 us; speedup vs baseline: 1.5769x; 1.5769x over previous
//
#include <hip/hip_runtime.h>

// LSTM B=1024 T=512 H=256 (input_size=1, output_size=1) on MI355X.
// R7: fix R6's rule-#20 scratch disaster. R6 post-mortem: VGPR=68,
// WRITE_SIZE 311MB, FETCH 2.1GB -> wv[4][8] indexed by RUNTIME kOwn=4*q
// went to scratch; every MFMA re-fetched weights from memory. Fix: load
// own-K-half into wvO[4][4] and partner-K-half into wvP[4][4] at init
// (runtime q only in the ADDRESS, never the array index) -> 128 VGPR of
// weights truly register-resident, zero per-step weight traffic.
// Also: own-half MFMAs BEFORE the partner poll (partner gets ~400cy more
// to publish), lane-0-only flag poll (wave is exec-mask synchronous),
// x-prefetch after flag release, skip partner MFMAs at t=0 (A==0).
// Structure recap: 128 blocks x 512 thr; pair (bid, bid^8) shares 16 batch
// rows; member q owns hidden cols [128q,128q+128), all 4 gates. Per step:
// publish own 16x128 h-half (4KB) via agent-scope stores + per-wave release
// atomicAdd flag; consume partner half via acquire poll + agent loads.
// Co-residency: 128 blocks <= 256 CUs -> no deadlock. One barrier/step.

#define HID 256
#define TT 512
#define NBLK 128
#define THREADS 512
#define HPAD2 136   // 128 local cols + 8 pad (ushort units)

typedef float v4f __attribute__((ext_vector_type(4)));
typedef unsigned int v4u __attribute__((ext_vector_type(4)));
typedef unsigned long long v2ul __attribute__((ext_vector_type(2)));
typedef __bf16 v8bf __attribute__((ext_vector_type(8)));

__device__ __forceinline__ unsigned short f2bf(float f) {
    unsigned int u = __builtin_bit_cast(unsigned int, f);
    u += 0x7fffu + ((u >> 16) & 1u);   // RNE
    return (unsigned short)(u >> 16);
}
__device__ __forceinline__ float bf2f(unsigned short s) {
    unsigned int u = ((unsigned int)s) << 16;
    return __builtin_bit_cast(float, u);
}
__device__ __forceinline__ float fsigmoid(float x) {
    float e = exp2f(x * -1.44269504f);
    return __builtin_amdgcn_rcpf(1.0f + e);
}
__device__ __forceinline__ float ftanh(float x) {
    float e = exp2f(x * 2.88539008f);
    return 1.0f - 2.0f * __builtin_amdgcn_rcpf(1.0f + e);
}

// W_hh fp32 [1024][256] -> bf16 fragment order:
// Wbf[((Tn*8+kc)*64+lane)*8 + j] = bf16(W_hh[16*Tn+(lane&15)][32*kc+(lane>>4)*8+j])
__global__ void wconv_kernel(const float* __restrict__ Whh,
                             unsigned short* __restrict__ Wbf) {
    int tid = blockIdx.x * blockDim.x + threadIdx.x;   // 0..32767
    int lane = tid & 63;
    int frag = tid >> 6;
    int Tn = frag >> 3;
    int kc = frag & 7;
    int n  = Tn * 16 + (lane & 15);
    int kb = kc * 32 + (lane >> 4) * 8;
    const float* src = Whh + (size_t)n * HID + kb;
    unsigned short* dst = Wbf + (size_t)tid * 8;
#pragma unroll
    for (int j = 0; j < 8; ++j) dst[j] = f2bf(src[j]);
}

#define MFMA_BF16 __builtin_amdgcn_mfma_f32_16x16x32_bf16

__global__ __launch_bounds__(THREADS, 1)
void lstm_kernel(const float* __restrict__ x,
                 const float* __restrict__ W_ih,
                 const float* __restrict__ b_ih,
                 const float* __restrict__ b_hh,
                 const float* __restrict__ W_lin,
                 const float* __restrict__ b_lin,
                 const unsigned short* __restrict__ Wbf,
                 unsigned short* __restrict__ Hx,
                 int* __restrict__ flags,
                 float* __restrict__ out) {
    __shared__ __align__(16) unsigned short hbuf[2][16 * HPAD2];  // 8.7 KB
    __shared__ float part[THREADS];                               // 2 KB

    const int tid  = threadIdx.x;
    const int lane = tid & 63;
    const int w    = tid >> 6;      // wave 0..7
    const int l4   = lane & 15;
    const int quad = lane >> 4;

    const int bid = blockIdx.x;
    const int q   = (bid >> 3) & 1;                 // gate-half role
    const int p   = (bid >> 4) * 8 + (bid & 7);     // pair id 0..63
    const int r0  = p * 16;                         // batch rows [r0, r0+16)

    // Hx layout: [parity][pair][q][16 rows][128 cols] bf16; parity stride:
    const size_t PSTR = (size_t)64 * 2 * 2048;
    unsigned short* HxMine       = Hx + (size_t)(p * 2 + q) * 2048;
    const unsigned short* HxPart = Hx + (size_t)(p * 2 + (1 - q)) * 2048;
    int* flagMine = flags + (p * 2 + q) * 32;       // 128B-spaced
    int* flagPart = flags + (p * 2 + (1 - q)) * 32;

    // Register-resident weights, STATICALLY indexed (rule #20):
    // wvO[G][k] = own K-half chunk (global kc = 4q+k), pairs with aOwn[k]
    // wvP[G][k] = partner K-half  (global kc = 4(1-q)+k), pairs with aP[k]
    v8bf wvO[4][4], wvP[4][4];
    {
        int n  = 8 * q + w;          // col-tile index 0..15
        int kO = 4 * q, kP = 4 - 4 * q;
#pragma unroll
        for (int G = 0; G < 4; ++G) {
            int Tn = 16 * G + n;
#pragma unroll
            for (int k = 0; k < 4; ++k) {
                wvO[G][k] = __builtin_bit_cast(v8bf, *(const v4u*)(Wbf +
                    ((size_t)(Tn * 8 + kO + k) * 64 + lane) * 8));
                wvP[G][k] = __builtin_bit_cast(v8bf, *(const v4u*)(Wbf +
                    ((size_t)(Tn * 8 + kP + k) * 64 + lane) * 8));
            }
        }
    }

    // per-thread gate constants
    const int col = 128 * q + 16 * w + l4;          // global hidden col
    const float cwi = W_ih[col],       cbi = b_ih[col]       + b_hh[col];
    const float cwf = W_ih[256 + col], cbf = b_ih[256 + col] + b_hh[256 + col];
    const float cwg = W_ih[512 + col], cbg = b_ih[512 + col] + b_hh[512 + col];
    const float cwo = W_ih[768 + col], cbo = b_ih[768 + col] + b_hh[768 + col];

    for (int i = tid; i < 16 * HPAD2; i += THREADS) hbuf[0][i] = 0;

    float xv[4];
#pragma unroll
    for (int r = 0; r < 4; ++r) xv[r] = x[(size_t)(r0 + quad * 4 + r) * TT];

    __syncthreads();

    float c_st[4] = {0.f, 0.f, 0.f, 0.f};
    int cur = 0;

    for (int t = 0; t < TT; ++t) {
        const unsigned short* hrow = hbuf[cur] + l4 * HPAD2 + quad * 8;
        unsigned short* hn = hbuf[cur ^ 1];

        v4f ai, af, ag, ao;
#pragma unroll
        for (int r = 0; r < 4; ++r) {
            ai[r] = xv[r] * cwi + cbi;
            af[r] = xv[r] * cwf + cbf;
            ag[r] = xv[r] * cwg + cbg;
            ao[r] = xv[r] * cwo + cbo;
        }

        // own-half MFMAs first (gives partner time to publish)
#pragma unroll
        for (int k = 0; k < 4; ++k) {
            v8bf a = __builtin_bit_cast(v8bf, *(const v4u*)(hrow + k * 32));
            ai = MFMA_BF16(a, wvO[0][k], ai, 0, 0, 0);
            af = MFMA_BF16(a, wvO[1][k], af, 0, 0, 0);
            ag = MFMA_BF16(a, wvO[2][k], ag, 0, 0, 0);
            ao = MFMA_BF16(a, wvO[3][k], ao, 0, 0, 0);
        }

        if (t > 0) {
            // lane-0 poll; wave is exec-mask synchronous, acquire's
            // waitcnt+inv are wave-level and precede the aP loads
            if (lane == 0) {
                while (__hip_atomic_load(flagPart, __ATOMIC_ACQUIRE,
                                         __HIP_MEMORY_SCOPE_AGENT) < 8 * t)
                    __builtin_amdgcn_s_sleep(1);
            }
            const unsigned long long* pb = (const unsigned long long*)
                (HxPart + ((t & 1) ? PSTR : 0) + l4 * 128 + quad * 8);
#pragma unroll
            for (int k = 0; k < 4; ++k) {
                v2ul tt;
                tt[0] = __hip_atomic_load(pb + k * 8, __ATOMIC_RELAXED,
                                          __HIP_MEMORY_SCOPE_AGENT);
                tt[1] = __hip_atomic_load(pb + k * 8 + 1, __ATOMIC_RELAXED,
                                          __HIP_MEMORY_SCOPE_AGENT);
                v8bf a = __builtin_bit_cast(v8bf, tt);
                ai = MFMA_BF16(a, wvP[0][k], ai, 0, 0, 0);
                af = MFMA_BF16(a, wvP[1][k], af, 0, 0, 0);
                ag = MFMA_BF16(a, wvP[2][k], ag, 0, 0, 0);
                ao = MFMA_BF16(a, wvP[3][k], ao, 0, 0, 0);
            }
        }

#pragma unroll
        for (int r = 0; r < 4; ++r) {
            float gi = fsigmoid(ai[r]);
            float gf = fsigmoid(af[r]);
            float gg = ftanh(ag[r]);
            float go = fsigmoid(ao[r]);
            float cn = gf * c_st[r] + gi * gg;
            c_st[r] = cn;
            hn[(quad * 4 + r) * HPAD2 + 16 * w + l4] = f2bf(go * ftanh(cn));
        }
        __syncthreads();

        // publish own half: [16][128] row-major, 8B per thread from LDS
        {
            int rr = tid >> 5, ch = tid & 31;
            unsigned long long v =
                *(const unsigned long long*)(hn + rr * HPAD2 + ch * 4);
            __hip_atomic_store((unsigned long long*)
                (HxMine + (((t + 1) & 1) ? PSTR : 0) + rr * 128 + ch * 4),
                v, __ATOMIC_RELAXED, __HIP_MEMORY_SCOPE_AGENT);
        }
        asm volatile("s_waitcnt vmcnt(0)" ::: "memory");
        if (lane == 0)
            __hip_atomic_fetch_add(flagMine, 1, __ATOMIC_RELEASE,
                                   __HIP_MEMORY_SCOPE_AGENT);

        // x prefetch for t+1 (after flag release so vmcnt(0) skips it)
        {
            int tn = (t + 1) & (TT - 1);
#pragma unroll
            for (int r = 0; r < 4; ++r)
                xv[r] = x[(size_t)(r0 + quad * 4 + r) * TT + tn];
        }
        cur ^= 1;
    }

    // Epilogue: q=0 combines both halves; partner final h in parity-0 slot.
    if (q == 0) {
        if (lane == 0) {
            while (__hip_atomic_load(flagPart, __ATOMIC_ACQUIRE,
                                     __HIP_MEMORY_SCOPE_AGENT) < 8 * TT)
                __builtin_amdgcn_s_sleep(1);
        }
        int rr = tid >> 5, ch = tid & 31;
        float ps = 0.f;
        if (ch < 16) {   // cols 0..127 from LDS
            const unsigned short* hb = hbuf[cur] + rr * HPAD2 + ch * 8;
#pragma unroll
            for (int jj = 0; jj < 8; ++jj)
                ps += bf2f(hb[jj]) * W_lin[ch * 8 + jj];
        } else {         // cols 128..255 from partner
            const unsigned long long* pb = (const unsigned long long*)
                (HxPart + rr * 128 + (ch - 16) * 8);
            unsigned long long lo = __hip_atomic_load(pb, __ATOMIC_RELAXED,
                                                      __HIP_MEMORY_SCOPE_AGENT);
            unsigned long long hi = __hip_atomic_load(pb + 1, __ATOMIC_RELAXED,
                                                      __HIP_MEMORY_SCOPE_AGENT);
            int cb = 128 + (ch - 16) * 8;
#pragma unroll
            for (int jj = 0; jj < 4; ++jj) {
                ps += bf2f((unsigned short)(lo >> (16 * jj))) * W_lin[cb + jj];
                ps += bf2f((unsigned short)(hi >> (16 * jj))) * W_lin[cb + 4 + jj];
            }
        }
        part[tid] = ps;
        __syncthreads();
        if (tid < 16) {
            float sum = 0.f;
#pragma unroll
            for (int s = 0; s < 32; ++s) sum += part[tid * 32 + s];
            out[r0 + tid] = sum + b_lin[0];
        }
    }
}

extern "C" void kernel_launch(void* const* d_in, const int* in_sizes, int n_in,
                              void* d_out, int out_size, void* d_ws, size_t ws_size,
                              hipStream_t stream) {
    const float* x     = (const float*)d_in[0];
    const float* W_ih  = (const float*)d_in[1];
    const float* W_hh  = (const float*)d_in[2];
    const float* b_ih  = (const float*)d_in[3];
    const float* b_hh  = (const float*)d_in[4];
    const float* W_lin = (const float*)d_in[5];
    const float* b_lin = (const float*)d_in[6];

    unsigned short* Wbf = (unsigned short*)d_ws;                          // 512 KB
    unsigned short* Hx  = (unsigned short*)((char*)d_ws + (512 << 10));   // 1 MB
    int* flags          = (int*)((char*)d_ws + (512 << 10) + (1024 << 10)); // 16 KB

    hipMemsetAsync(flags, 0, 64 * 2 * 32 * sizeof(int), stream);
    wconv_kernel<<<128, 256, 0, stream>>>(W_hh, Wbf);
    lstm_kernel<<<NBLK, THREADS, 0, stream>>>(x, W_ih, b_ih, b_hh, W_lin, b_lin,
                                              Wbf, Hx, flags, (float*)d_out);
}

// Round 4
// 6857.430 us; speedup vs baseline: 2.8595x; 1.8134x over previous
//
#include <hip/hip_runtime.h>

// LSTM B=1024 T=512 H=256 (input_size=1, output_size=1) on MI355X.
// R8: back to within-CU recurrence (R7 post-mortem: cross-CU pair-split pays
// >=2 L3 round-trips per step + scheduling jitter -> 24-100us/step, 278MB
// publish traffic; dead end). R4 (1583us) was latency-bound at 2 waves/SIMD
// (7400cy/step vs ~1700cy issue work). Fix TLP with correct launch-bounds
// semantics (2nd arg = min BLOCKS/CU): a 1024-thread block + (1024,1)
// physically forces <=128 VGPR and gives 4 waves/SIMD, guaranteed.
// Structure: 64 blocks x 1024 thr (16 waves). Wave w owns hidden cols
// [16w,16w+16) and all 4 of its gate tiles:
//   i (Tn=w):    register-resident (32 VGPR)
//   f,g,o (Tn=16+w,32+w,48+w): streamed from L2 via three rotating 16-reg
//     quarter-buffers, 4-kc prefetch distance; kc>=4 reloads are next-step
//     tiles in flight across the barrier. Unique stream data = 384KB,
//     L2-resident per XCD (8 blocks/XCD read the same lines each step).
// No weight LDS at all: LDS = 17KB h double-buffer only; LDS reads halve
// vs R4 (128 b128/CU-step for A-fragments). Per-step issue model:
// max(LDS 1536, L2 ~1680, VALU+trans ~1600, MFMA 614) ~ 1700cy with 4
// waves/SIMD overlapping pipes. Reg budget ~124 <= 128 (static indices
// everywhere per rule #20; kc&3 is compile-time after unroll).

#define HID 256
#define TT 512
#define NBLK 64
#define THREADS 1024
#define HPAD 264   // 256 cols + 8 pad (ushort units)

typedef float v4f __attribute__((ext_vector_type(4)));
typedef unsigned int v4u __attribute__((ext_vector_type(4)));
typedef __bf16 v8bf __attribute__((ext_vector_type(8)));

__device__ __forceinline__ unsigned short f2bf(float f) {
    unsigned int u = __builtin_bit_cast(unsigned int, f);
    u += 0x7fffu + ((u >> 16) & 1u);   // RNE
    return (unsigned short)(u >> 16);
}
__device__ __forceinline__ float bf2f(unsigned short s) {
    unsigned int u = ((unsigned int)s) << 16;
    return __builtin_bit_cast(float, u);
}
__device__ __forceinline__ float fsigmoid(float x) {
    float e = exp2f(x * -1.44269504f);
    return __builtin_amdgcn_rcpf(1.0f + e);
}
__device__ __forceinline__ float ftanh(float x) {
    float e = exp2f(x * 2.88539008f);
    return 1.0f - 2.0f * __builtin_amdgcn_rcpf(1.0f + e);
}

// W_hh fp32 [1024][256] -> bf16 fragment order:
// Wbf[((Tn*8+kc)*64+lane)*8 + j] = bf16(W_hh[16*Tn+(lane&15)][32*kc+(lane>>4)*8+j])
__global__ void wconv_kernel(const float* __restrict__ Whh,
                             unsigned short* __restrict__ Wbf) {
    int tid = blockIdx.x * blockDim.x + threadIdx.x;   // 0..32767
    int lane = tid & 63;
    int frag = tid >> 6;
    int Tn = frag >> 3;
    int kc = frag & 7;
    int n  = Tn * 16 + (lane & 15);
    int kb = kc * 32 + (lane >> 4) * 8;
    const float* src = Whh + (size_t)n * HID + kb;
    unsigned short* dst = Wbf + (size_t)tid * 8;
#pragma unroll
    for (int j = 0; j < 8; ++j) dst[j] = f2bf(src[j]);
}

#define MFMA_BF16 __builtin_amdgcn_mfma_f32_16x16x32_bf16

__global__ __launch_bounds__(THREADS, 1)
void lstm_kernel(const float* __restrict__ x,
                 const float* __restrict__ W_ih,
                 const float* __restrict__ b_ih,
                 const float* __restrict__ b_hh,
                 const float* __restrict__ W_lin,
                 const float* __restrict__ b_lin,
                 const unsigned short* __restrict__ Wbf,
                 float* __restrict__ out) {
    __shared__ __align__(16) unsigned short hbuf[2][16 * HPAD];   // 16.9 KB

    const int tid  = threadIdx.x;
    const int lane = tid & 63;
    const int w    = tid >> 6;      // wave 0..15; owns cols [16w, 16w+16)
    const int l4   = lane & 15;
    const int quad = lane >> 4;
    const int r0   = blockIdx.x * 16;
    const int col  = 16 * w + l4;   // this thread's hidden column

    // i-gate tile register-resident (Tn = w): 32 VGPR
    v8bf wi[8];
#pragma unroll
    for (int kc = 0; kc < 8; ++kc)
        wi[kc] = __builtin_bit_cast(v8bf,
            *((const v4u*)Wbf + ((size_t)(w * 8 + kc)) * 64 + lane));

    // stream bases for f, g, o (v4u-indexed; tiles 16+w, 32+w, 48+w)
    const v4u* fptr = (const v4u*)Wbf + ((size_t)(16 + w) * 8) * 64 + lane;
    const v4u* gptr = fptr + (size_t)16 * 8 * 64;   // +16 tiles
    const v4u* optr = fptr + (size_t)32 * 8 * 64;   // +32 tiles

    // rotating quarter buffers; prologue holds kc 0..3
    v4u fb[4], gb[4], ob[4];
#pragma unroll
    for (int j = 0; j < 4; ++j) {
        fb[j] = fptr[j * 64];
        gb[j] = gptr[j * 64];
        ob[j] = optr[j * 64];
    }

    // per-thread gate constants
    const float cwi = W_ih[col],       cbi = b_ih[col]       + b_hh[col];
    const float cwf = W_ih[256 + col], cbf = b_ih[256 + col] + b_hh[256 + col];
    const float cwg = W_ih[512 + col], cbg = b_ih[512 + col] + b_hh[512 + col];
    const float cwo = W_ih[768 + col], cbo = b_ih[768 + col] + b_hh[768 + col];

    for (int i = tid; i < 16 * HPAD; i += THREADS) hbuf[0][i] = 0;

    float xv[4];
#pragma unroll
    for (int r = 0; r < 4; ++r) xv[r] = x[(size_t)(r0 + quad * 4 + r) * TT];

    __syncthreads();

    float c_st[4] = {0.f, 0.f, 0.f, 0.f};
    int cur = 0;

    for (int t = 0; t < TT; ++t) {
        const unsigned short* hrow = hbuf[cur] + l4 * HPAD + quad * 8;
        unsigned short* hn = hbuf[cur ^ 1];

        v4f ai, af, ag, ao;
#pragma unroll
        for (int r = 0; r < 4; ++r) {
            ai[r] = xv[r] * cwi + cbi;
            af[r] = xv[r] * cwf + cbf;
            ag[r] = xv[r] * cwg + cbg;
            ao[r] = xv[r] * cwo + cbo;
        }

#pragma unroll
        for (int kc = 0; kc < 8; ++kc) {
            v8bf a = __builtin_bit_cast(v8bf, *(const v4u*)(hrow + kc * 32));
            ai = MFMA_BF16(a, wi[kc], ai, 0, 0, 0);
            af = MFMA_BF16(a, __builtin_bit_cast(v8bf, fb[kc & 3]), af, 0, 0, 0);
            ag = MFMA_BF16(a, __builtin_bit_cast(v8bf, gb[kc & 3]), ag, 0, 0, 0);
            ao = MFMA_BF16(a, __builtin_bit_cast(v8bf, ob[kc & 3]), ao, 0, 0, 0);
            // reload just-consumed quarter: kc<4 -> kc+4 (later this step),
            // kc>=4 -> kc-4 (next step; stays in flight across the barrier)
            fb[kc & 3] = fptr[((kc + 4) & 7) * 64];
            gb[kc & 3] = gptr[((kc + 4) & 7) * 64];
            ob[kc & 3] = optr[((kc + 4) & 7) * 64];
        }

#pragma unroll
        for (int r = 0; r < 4; ++r) {
            float gi = fsigmoid(ai[r]);
            float gf = fsigmoid(af[r]);
            float gg = ftanh(ag[r]);
            float go = fsigmoid(ao[r]);
            float cn = gf * c_st[r] + gi * gg;
            c_st[r] = cn;
            hn[(quad * 4 + r) * HPAD + col] = f2bf(go * ftanh(cn));
        }

        // x prefetch for t+1 (wraps harmlessly at the end)
        {
            int tn = (t + 1) & (TT - 1);
#pragma unroll
            for (int r = 0; r < 4; ++r)
                xv[r] = x[(size_t)(r0 + quad * 4 + r) * TT + tn];
        }

        __syncthreads();
        cur ^= 1;
    }

    // Epilogue: wave w reduces batch row w: out[r0+w] = h . W_lin + b_lin
    float p = 0.f;
#pragma unroll
    for (int j = 0; j < 4; ++j) {
        int c = lane * 4 + j;
        p += bf2f(hbuf[cur][w * HPAD + c]) * W_lin[c];
    }
#pragma unroll
    for (int off = 32; off; off >>= 1) p += __shfl_down(p, off);
    if (lane == 0) out[r0 + w] = p + b_lin[0];
}

extern "C" void kernel_launch(void* const* d_in, const int* in_sizes, int n_in,
                              void* d_out, int out_size, void* d_ws, size_t ws_size,
                              hipStream_t stream) {
    const float* x     = (const float*)d_in[0];
    const float* W_ih  = (const float*)d_in[1];
    const float* W_hh  = (const float*)d_in[2];
    const float* b_ih  = (const float*)d_in[3];
    const float* b_hh  = (const float*)d_in[4];
    const float* W_lin = (const float*)d_in[5];
    const float* b_lin = (const float*)d_in[6];
    unsigned short* Wbf = (unsigned short*)d_ws;   // 512 KB

    wconv_kernel<<<128, 256, 0, stream>>>(W_hh, Wbf);
    lstm_kernel<<<NBLK, THREADS, 0, stream>>>(x, W_ih, b_ih, b_hh, W_lin, b_lin,
                                              Wbf, (float*)d_out);
}